// Round 5
// baseline (624.313 us; speedup 1.0000x reference)
//
#include <hip/hip_runtime.h>

#define T_STEPS 144000
#define HDIM 128
#define G4 512
#define NB 10
#define CH 16
#define EPS 1e-4f
#define WIN 8
#define SENT 0x7fffffff
#define RING0 4096
#define R0M (RING0-1)
#define RING1 1024
#define R1M (RING1-1)
#define FILL_BASE 6
#define NBLK 512

__device__ __forceinline__ float sigf(float x){ return 1.f/(1.f+__expf(-x)); }
__device__ __forceinline__ float tanh_(float x){
  float e2 = __expf(-2.f*fabsf(x));
  float r = (1.f - e2)/(1.f + e2);
  return copysignf(r, x);
}

// flags: [0,1]=prog0  [2,3]=T0p1  [4,5]=progP  [6,7]=progC  [8,9]=T1p1  [10]=wrdy
__global__ __launch_bounds__(512) void k_all(
    const float* __restrict__ x, const float* __restrict__ w1, const float* __restrict__ b1,
    const float* __restrict__ w2, const float* __restrict__ b2,
    const float* __restrict__ w_ih0, const float* __restrict__ b_ih0, const float* __restrict__ b_hh0,
    const float* __restrict__ w_ih1, const float* __restrict__ w_hh0, const float* __restrict__ w_hh1,
    const float* __restrict__ b_ih1, const float* __restrict__ b_hh1,
    const float* __restrict__ w_out, const float* __restrict__ b_out,
    int* __restrict__ flags, float* __restrict__ outst, float* __restrict__ wih1T,
    float* __restrict__ hs0, float* __restrict__ xproj1, float* __restrict__ out)
{
  __shared__ __align__(16) float sm[2304];   // 9216 B, role-aliased
  int* ip  = (int*)&sm[832];                 // producer/consumer: okw[2], sAv, sT0
  int* ip2 = (int*)&sm[2048];                // projector: sAv, sT0
  const int blk = blockIdx.x;
  const int j = threadIdx.x;
  const int gt = j >> 7;                     // gate type 0:i 1:f 2:g 3:o (wave-uniform)
  int* prog0 = flags + 0; int* T0p1 = flags + 2; int* progP = flags + 4;
  int* progC = flags + 6; int* T1p1 = flags + 8; int* wrdy  = flags + 10;

  if (blk < 2) {
    // ===================== layer-0 producer (batch b) =====================
    const int b = blk;
    float* gls = sm; float* hls = sm + 512; float* lat1s = sm + 640; float* lat2s = sm + 704;
    // inline encoder MLP
    if (j < 64) {
      float a = b1[j];
      #pragma unroll
      for (int k = 0; k < 16; k++) a += x[b*16+k] * w1[j*16+k];
      lat1s[j] = fmaxf(a, 0.f);
    }
    __syncthreads();
    if (j < 128) {
      float a = b2[j];
      #pragma unroll
      for (int k = 0; k < 64; k++) a += lat1s[k] * w2[j*64+k];
      lat2s[j] = fmaxf(a, 0.f);
    }
    __syncthreads();
    float xp = b_ih0[j] + b_hh0[j];
    {
      const float4* wi = (const float4*)(w_ih0 + j*128);
      const float4* l2 = (const float4*)lat2s;
      #pragma unroll
      for (int k = 0; k < 32; k++) {
        float4 wv = wi[k], lv = l2[k];
        xp += wv.x*lv.x + wv.y*lv.y + wv.z*lv.z + wv.w*lv.w;
      }
    }
    float4 w4[32];
    const float4* wr = (const float4*)(w_hh0 + j*128);
    #pragma unroll
    for (int k = 0; k < 32; k++) w4[k] = wr[k];
    float* hb = hs0 + (size_t)b * RING0 * HDIM;
    if (j < HDIM) hls[j] = 0.f;
    const int d = j & 127;
    float c = 0.f, hp = 0.f;
    int cnt = 0;
    __syncthreads();
    int t = 0;
    for (; t < T_STEPS; ++t) {
      float a0 = xp, a1 = 0.f, a2 = 0.f, a3 = 0.f;
      const float4* h4 = (const float4*)hls;
      #pragma unroll
      for (int k = 0; k < 32; k++) {
        float4 hv = h4[k];
        a0 += w4[k].x*hv.x; a1 += w4[k].y*hv.y; a2 += w4[k].z*hv.z; a3 += w4[k].w*hv.w;
      }
      float pre = (a0+a1)+(a2+a3);
      gls[j] = (gt == 2) ? tanh_(pre) : sigf(pre);
      __syncthreads();                                   // bar1
      float ii = gls[d], ff = gls[128+d], gg = gls[256+d], oo = gls[384+d];
      float nc = ff*c + ii*gg;
      float nh = oo*tanh_(nc);
      bool ok = fabsf(nh-hp) <= EPS && fabsf(nc-c) <= EPS*fmaxf(1.f, fabsf(nc));
      c = nc; hp = nh;
      if (j < 128) {
        hls[j] = nh;
        unsigned long long bal = __ballot(ok);
        if ((j & 63) == 0) ip[j >> 6] = (bal == ~0ull) ? 1 : 0;
      }
      __syncthreads();                                   // bar2
      if (j < 128) hb[(t & R0M)*HDIM + j] = nh;          // store drains at a later barrier
      cnt = (ip[0] && ip[1]) ? cnt + 1 : 0;
      bool conv = (cnt >= WIN);
      bool ce = ((t & (CH-1)) == (CH-1));
      if (ce || conv) {
        __syncthreads();                                 // drain chunk's global stores
        if (j == 0) {
          __threadfence();
          __hip_atomic_store(&prog0[b], t+1, __ATOMIC_RELEASE, __HIP_MEMORY_SCOPE_AGENT);
          if (!conv) {
            while ((t + 1 + CH) - __hip_atomic_load(&progP[b], __ATOMIC_ACQUIRE, __HIP_MEMORY_SCOPE_AGENT) > RING0)
              __builtin_amdgcn_s_sleep(2);
          }
        }
      }
      if (conv) { ++t; break; }
    }
    if (j == 0) {
      __threadfence();
      __hip_atomic_store(&prog0[b], t, __ATOMIC_RELEASE, __HIP_MEMORY_SCOPE_AGENT);
      __hip_atomic_store(&T0p1[b], t+1, __ATOMIC_RELEASE, __HIP_MEMORY_SCOPE_AGENT);
    }
  } else if (blk < 4) {
    // ===================== projector: xproj1 = w_ih1 . h0 + bias =====================
    const int b = blk & 1;
    float* s0ls = sm;
    if (j == 0) {
      while (__hip_atomic_load(wrdy, __ATOMIC_ACQUIRE, __HIP_MEMORY_SCOPE_AGENT) == 0)
        __builtin_amdgcn_s_sleep(2);
    }
    __syncthreads();
    __threadfence();
    const float bias = b_ih1[j] + b_hh1[j];
    const float* hb = hs0 + (size_t)b * RING0 * HDIM;
    float* xp1b = xproj1 + (size_t)b * RING1 * G4;
    int t = 0;
    for (;;) {
      if (j == 0) {
        int av, tv;
        for (;;) {
          av = __hip_atomic_load(&prog0[b], __ATOMIC_ACQUIRE, __HIP_MEMORY_SCOPE_AGENT);
          tv = __hip_atomic_load(&T0p1[b], __ATOMIC_ACQUIRE, __HIP_MEMORY_SCOPE_AGENT);
          int T0v = (tv == 0) ? SENT : tv - 1;
          if (T0v != SENT && t >= T0v) break;
          int need = t + CH; if (T0v != SENT && T0v < need) need = T0v;
          int cons = __hip_atomic_load(&progC[b], __ATOMIC_ACQUIRE, __HIP_MEMORY_SCOPE_AGENT);
          if (av >= need && need <= cons + RING1) break;
          __builtin_amdgcn_s_sleep(2);
        }
        ip2[0] = av; ip2[1] = tv;
      }
      __syncthreads();
      __threadfence();
      int av = ip2[0], tv = ip2[1];
      int T0v = (tv == 0) ? SENT : tv - 1;
      if (T0v != SENT && t >= T0v) break;
      int lim = (T0v != SENT && T0v < av) ? T0v : av;
      int C = min(CH, lim - t);
      for (int idx = j; idx < CH*HDIM; idx += 512) {
        int cc = idx >> 7, lane = idx & 127;
        float v = 0.f;
        if (cc < C) v = hb[((t + cc) & R0M)*HDIM + lane];
        s0ls[idx] = v;
      }
      __syncthreads();
      float xpa[CH];
      #pragma unroll
      for (int cc = 0; cc < CH; cc++) xpa[cc] = 0.f;
      const float4* s04 = (const float4*)s0ls;
      for (int k4 = 0; k4 < 32; k4++) {
        float wv0 = wih1T[(4*k4+0)*G4 + j];
        float wv1 = wih1T[(4*k4+1)*G4 + j];
        float wv2 = wih1T[(4*k4+2)*G4 + j];
        float wv3 = wih1T[(4*k4+3)*G4 + j];
        #pragma unroll
        for (int cc = 0; cc < CH; cc++) {
          float4 sv = s04[cc*32 + k4];
          xpa[cc] += wv0*sv.x + wv1*sv.y + wv2*sv.z + wv3*sv.w;
        }
      }
      for (int cc = 0; cc < C; cc++)
        xp1b[((t + cc) & R1M)*G4 + j] = xpa[cc] + bias;
      __syncthreads();
      if (j == 0) {
        __threadfence();
        __hip_atomic_store(&progP[b], t + C, __ATOMIC_RELEASE, __HIP_MEMORY_SCOPE_AGENT);
      }
      t += C;
    }
  } else if (blk < 6) {
    // ===================== layer-1 consumer + fused head =====================
    const int b = blk & 1;
    float* gls = sm; float* hls = sm + 512; float* s0b = sm + 640;
    float4 w4[32];
    const float4* wr = (const float4*)(w_hh1 + j*128);
    #pragma unroll
    for (int k = 0; k < 32; k++) w4[k] = wr[k];
    const float bias = b_ih1[j] + b_hh1[j];
    const int hn = j >> 5, hseg = j & 31;
    float4 wo = make_float4(0.f,0.f,0.f,0.f); float bo = 0.f;
    if (j < 320) { wo = ((const float4*)(w_out + hn*128))[hseg]; bo = b_out[hn]; }
    float* outb = out + (size_t)b * T_STEPS * NB;
    const float* hb = hs0 + (size_t)b * RING0 * HDIM;
    const float* xp1b = xproj1 + (size_t)b * RING1 * G4;
    if (j < HDIM) hls[j] = 0.f;
    const int d = j & 127;
    float c = 0.f, hp = 0.f;
    int cnt = 0;
    __syncthreads();
    int t = 0, T0fin = T_STEPS;

    // Phase A: t < T0, input from xproj1 ring
    for (;;) {
      if (j == 0) {
        int pv, tv;
        for (;;) {
          pv = __hip_atomic_load(&progP[b], __ATOMIC_ACQUIRE, __HIP_MEMORY_SCOPE_AGENT);
          tv = __hip_atomic_load(&T0p1[b], __ATOMIC_ACQUIRE, __HIP_MEMORY_SCOPE_AGENT);
          int T0v = (tv == 0) ? SENT : tv - 1;
          if (T0v != SENT && t >= T0v) break;
          int need = t + CH; if (T0v != SENT && T0v < need) need = T0v;
          if (pv >= need) break;
          __builtin_amdgcn_s_sleep(2);
        }
        ip[2] = pv; ip[3] = tv;
      }
      __syncthreads();
      __threadfence();
      int pv = ip[2], tv = ip[3];
      int T0v = (tv == 0) ? SENT : tv - 1;
      if (T0v != SENT && t >= T0v) { T0fin = T0v; break; }
      int lim = (T0v != SENT && T0v < pv) ? T0v : pv;
      int C = min(CH, lim - t);
      float xpa[CH];
      #pragma unroll
      for (int cc = 0; cc < CH; cc++)
        xpa[cc] = xp1b[((t + cc) & R1M)*G4 + j];
      for (int cc = 0; cc < C; cc++) {
        float a0 = xpa[cc], a1 = 0.f, a2 = 0.f, a3 = 0.f;
        const float4* h4 = (const float4*)hls;
        #pragma unroll
        for (int k = 0; k < 32; k++) {
          float4 hv = h4[k];
          a0 += w4[k].x*hv.x; a1 += w4[k].y*hv.y; a2 += w4[k].z*hv.z; a3 += w4[k].w*hv.w;
        }
        float pre = (a0+a1)+(a2+a3);
        gls[j] = (gt == 2) ? tanh_(pre) : sigf(pre);
        __syncthreads();
        float ii = gls[d], ff = gls[128+d], gg = gls[256+d], oo = gls[384+d];
        float nc = ff*c + ii*gg;
        float nh = oo*tanh_(nc);
        c = nc; hp = nh;
        if (j < 128) hls[j] = nh;
        __syncthreads();
        if (j < 320) {
          float4 hv = ((const float4*)hls)[hseg];
          float acc = wo.x*hv.x + wo.y*hv.y + wo.z*hv.z + wo.w*hv.w;
          acc += __shfl_xor(acc, 1, 32);
          acc += __shfl_xor(acc, 2, 32);
          acc += __shfl_xor(acc, 4, 32);
          acc += __shfl_xor(acc, 8, 32);
          acc += __shfl_xor(acc, 16, 32);
          if (hseg == 0) outb[(t+cc)*NB + hn] = acc + bo;
        }
      }
      if (j == 0) __hip_atomic_store(&progC[b], t + C, __ATOMIC_RELEASE, __HIP_MEMORY_SCOPE_AGENT);
      t += C;
    }

    // Phase B: constant input, convergence detect
    if (T0fin < T_STEPS) {
      if (j < HDIM) s0b[j] = hb[((T0fin-1) & R0M)*HDIM + j];
      __syncthreads();
      float xps = bias;
      const float4* s04 = (const float4*)s0b;
      #pragma unroll
      for (int k4 = 0; k4 < 32; k4++) {
        float4 sv = s04[k4];
        xps += wih1T[(4*k4+0)*G4 + j]*sv.x + wih1T[(4*k4+1)*G4 + j]*sv.y
             + wih1T[(4*k4+2)*G4 + j]*sv.z + wih1T[(4*k4+3)*G4 + j]*sv.w;
      }
      for (; t < T_STEPS; ++t) {
        float a0 = xps, a1 = 0.f, a2 = 0.f, a3 = 0.f;
        const float4* h4 = (const float4*)hls;
        #pragma unroll
        for (int k = 0; k < 32; k++) {
          float4 hv = h4[k];
          a0 += w4[k].x*hv.x; a1 += w4[k].y*hv.y; a2 += w4[k].z*hv.z; a3 += w4[k].w*hv.w;
        }
        float pre = (a0+a1)+(a2+a3);
        gls[j] = (gt == 2) ? tanh_(pre) : sigf(pre);
        __syncthreads();
        float ii = gls[d], ff = gls[128+d], gg = gls[256+d], oo = gls[384+d];
        float nc = ff*c + ii*gg;
        float nh = oo*tanh_(nc);
        bool ok = fabsf(nh-hp) <= EPS && fabsf(nc-c) <= EPS*fmaxf(1.f, fabsf(nc));
        c = nc; hp = nh;
        if (j < 128) {
          hls[j] = nh;
          unsigned long long bal = __ballot(ok);
          if ((j & 63) == 0) ip[j >> 6] = (bal == ~0ull) ? 1 : 0;
        }
        __syncthreads();
        if (j < 320) {
          float4 hv = ((const float4*)hls)[hseg];
          float acc = wo.x*hv.x + wo.y*hv.y + wo.z*hv.z + wo.w*hv.w;
          acc += __shfl_xor(acc, 1, 32);
          acc += __shfl_xor(acc, 2, 32);
          acc += __shfl_xor(acc, 4, 32);
          acc += __shfl_xor(acc, 8, 32);
          acc += __shfl_xor(acc, 16, 32);
          if (hseg == 0) outb[t*NB + hn] = acc + bo;
        }
        cnt = (ip[0] && ip[1]) ? cnt + 1 : 0;
        if (cnt >= WIN) { ++t; break; }
      }
    }
    // publish T1 + outstar
    if (j < 320) {
      float4 hv = ((const float4*)hls)[hseg];
      float acc = wo.x*hv.x + wo.y*hv.y + wo.z*hv.z + wo.w*hv.w;
      acc += __shfl_xor(acc, 1, 32);
      acc += __shfl_xor(acc, 2, 32);
      acc += __shfl_xor(acc, 4, 32);
      acc += __shfl_xor(acc, 8, 32);
      acc += __shfl_xor(acc, 16, 32);
      if (hseg == 0) outst[b*NB + hn] = acc + bo;
    }
    __syncthreads();
    if (j == 0) {
      __threadfence();
      __hip_atomic_store(&T1p1[b], t + 1, __ATOMIC_RELEASE, __HIP_MEMORY_SCOPE_AGENT);
    }
  } else {
    // ===================== transposer (blk 6) then fill; blks 7.. fill =====================
    if (blk == 6) {
      float* tile = sm;  // [32][33]
      const int tx = j & 31, ty = j >> 5;  // ty 0..15
      for (int ti = 0; ti < 16; ti++) {
        for (int tk = 0; tk < 4; tk++) {
          #pragma unroll
          for (int p = 0; p < 2; p++)
            tile[(ty + 16*p)*33 + tx] = w_ih1[(ti*32 + ty + 16*p)*128 + tk*32 + tx];
          __syncthreads();
          #pragma unroll
          for (int p = 0; p < 2; p++)
            wih1T[(tk*32 + ty + 16*p)*G4 + ti*32 + tx] = tile[tx*33 + ty + 16*p];
          __syncthreads();
        }
      }
      if (j == 0) {
        __threadfence();
        __hip_atomic_store(wrdy, 1, __ATOMIC_RELEASE, __HIP_MEMORY_SCOPE_AGENT);
      }
    }
    // fill: wait for both T1, then write out* to the frozen tail
    if (j == 0) {
      int a, bb;
      do {
        a  = __hip_atomic_load(&T1p1[0], __ATOMIC_ACQUIRE, __HIP_MEMORY_SCOPE_AGENT);
        bb = __hip_atomic_load(&T1p1[1], __ATOMIC_ACQUIRE, __HIP_MEMORY_SCOPE_AGENT);
        if (a == 0 || bb == 0) __builtin_amdgcn_s_sleep(8);
      } while (a == 0 || bb == 0);
      ip[2] = a - 1; ip[3] = bb - 1;
    }
    __syncthreads();
    __threadfence();
    const int T1a = ip[2], T1b = ip[3];
    const int fblk = blk - FILL_BASE, nf = NBLK - FILL_BASE;
    const int total = 2*T_STEPS*NB;
    for (int idx = fblk*512 + j; idx < total; idx += nf*512) {
      int n = idx % NB;
      int bt = idx / NB;
      int t = bt % T_STEPS;
      int b = bt / T_STEPS;
      if (t >= (b ? T1b : T1a)) out[idx] = outst[b*NB + n];
    }
  }
}

extern "C" void kernel_launch(void* const* d_in, const int* in_sizes, int n_in,
                              void* d_out, int out_size, void* d_ws, size_t ws_size,
                              hipStream_t stream) {
  const float* x     = (const float*)d_in[0];
  const float* w1    = (const float*)d_in[1];
  const float* b1    = (const float*)d_in[2];
  const float* w2    = (const float*)d_in[3];
  const float* b2    = (const float*)d_in[4];
  const float* w_ih0 = (const float*)d_in[5];
  const float* w_hh0 = (const float*)d_in[6];
  const float* b_ih0 = (const float*)d_in[7];
  const float* b_hh0 = (const float*)d_in[8];
  const float* w_ih1 = (const float*)d_in[9];
  const float* w_hh1 = (const float*)d_in[10];
  const float* b_ih1 = (const float*)d_in[11];
  const float* b_hh1 = (const float*)d_in[12];
  const float* w_out = (const float*)d_in[13];
  const float* b_out = (const float*)d_in[14];
  float* out = (float*)d_out;

  char* ws = (char*)d_ws;
  int*   flags   = (int*)  (ws + 0);                 // 64 B (memset)
  float* outst   = (float*)(ws + 64);                // 80 B
  float* wih1T   = (float*)(ws + 4096);              // 256 KB
  float* hs0     = (float*)(ws + 270336);            // 2*4096*128*4 = 4 MB
  float* xproj1  = (float*)(ws + 270336 + 4194304);  // 2*1024*512*4 = 4 MB

  hipMemsetAsync(flags, 0, 64, stream);
  k_all<<<NBLK, 512, 0, stream>>>(x, w1, b1, w2, b2, w_ih0, b_ih0, b_hh0,
                                  w_ih1, w_hh0, w_hh1, b_ih1, b_hh1, w_out, b_out,
                                  flags, outst, wih1T, hs0, xproj1, out);
}

// Round 6
// 134.825 us; speedup vs baseline: 4.6305x; 4.6305x over previous
//
#include <hip/hip_runtime.h>

#define T_STEPS 144000
#define HDIM 128
#define G4 512
#define NB 10
#define CH 16
#define EPS 1e-4f
#define WIN 8
#define SENT 0x7fffffff
#define RING0 4096
#define R0M (RING0-1)
#define RING1 1024
#define R1M (RING1-1)

__device__ __forceinline__ float sigf(float x){ return 1.f/(1.f+__expf(-x)); }
__device__ __forceinline__ float tanh_(float x){
  float e2 = __expf(-2.f*fabsf(x));
  float r = (1.f - e2)/(1.f + e2);
  return copysignf(r, x);
}

// ---------------- K1: transpose w_ih1 [512][128] -> wih1T [128][512], 16 blocks ----------------
__global__ __launch_bounds__(256) void k1_transpose(const float* __restrict__ w_ih1,
                                                    float* __restrict__ wih1T)
{
  __shared__ float tile[32][33];
  const int ti = blockIdx.x;           // row-tile 0..15
  const int tx = threadIdx.x & 31, ty = threadIdx.x >> 5;  // ty 0..7
  for (int tk = 0; tk < 4; tk++) {
    #pragma unroll
    for (int p = 0; p < 4; p++)
      tile[ty + 8*p][tx] = w_ih1[(ti*32 + ty + 8*p)*128 + tk*32 + tx];
    __syncthreads();
    #pragma unroll
    for (int p = 0; p < 4; p++)
      wih1T[(tk*32 + ty + 8*p)*G4 + ti*32 + tx] = tile[tx][ty + 8*p];
    __syncthreads();
  }
}

// flags: [0,1]=prog0  [2,3]=T0p1  [4,5]=progP  [6,7]=progC  [8,9]=T1p1
__global__ __launch_bounds__(512) void k23_fused(
    const float* __restrict__ x, const float* __restrict__ w1, const float* __restrict__ b1,
    const float* __restrict__ w2, const float* __restrict__ b2,
    const float* __restrict__ w_ih0, const float* __restrict__ b_ih0, const float* __restrict__ b_hh0,
    const float* __restrict__ w_hh0, const float* __restrict__ w_hh1,
    const float* __restrict__ b_ih1, const float* __restrict__ b_hh1,
    const float* __restrict__ w_out, const float* __restrict__ b_out,
    const float* __restrict__ wih1T,
    int* __restrict__ flags, float* __restrict__ outst,
    float* __restrict__ hs0, float* __restrict__ xproj1, float* __restrict__ out)
{
  __shared__ __align__(16) float sm[2304];
  int* ip  = (int*)&sm[832];
  int* ip2 = (int*)&sm[2048];
  const int blk = blockIdx.x;
  const int j = threadIdx.x;
  const int gt = j >> 7;
  int* prog0 = flags + 0; int* T0p1 = flags + 2; int* progP = flags + 4;
  int* progC = flags + 6; int* T1p1 = flags + 8;

  if (blk < 2) {
    // ===================== layer-0 producer (batch b) =====================
    const int b = blk;
    float* gls = sm; float* hls = sm + 512; float* lat1s = sm + 640; float* lat2s = sm + 704;
    if (j < 64) {
      float a = b1[j];
      #pragma unroll
      for (int k = 0; k < 16; k++) a += x[b*16+k] * w1[j*16+k];
      lat1s[j] = fmaxf(a, 0.f);
    }
    __syncthreads();
    if (j < 128) {
      float a = b2[j];
      #pragma unroll
      for (int k = 0; k < 64; k++) a += lat1s[k] * w2[j*64+k];
      lat2s[j] = fmaxf(a, 0.f);
    }
    __syncthreads();
    float xp = b_ih0[j] + b_hh0[j];
    {
      const float4* wi = (const float4*)(w_ih0 + j*128);
      const float4* l2 = (const float4*)lat2s;
      #pragma unroll
      for (int k = 0; k < 32; k++) {
        float4 wv = wi[k], lv = l2[k];
        xp += wv.x*lv.x + wv.y*lv.y + wv.z*lv.z + wv.w*lv.w;
      }
    }
    float4 w4[32];
    const float4* wr = (const float4*)(w_hh0 + j*128);
    #pragma unroll
    for (int k = 0; k < 32; k++) w4[k] = wr[k];
    float* hb = hs0 + (size_t)b * RING0 * HDIM;
    if (j < HDIM) hls[j] = 0.f;
    const int d = j & 127;
    float c = 0.f, hp = 0.f;
    int cnt = 0;
    __syncthreads();
    int t = 0;
    for (; t < T_STEPS; ++t) {
      float a0 = xp, a1 = 0.f, a2 = 0.f, a3 = 0.f;
      const float4* h4 = (const float4*)hls;
      #pragma unroll
      for (int k = 0; k < 32; k++) {
        float4 hv = h4[k];
        a0 += w4[k].x*hv.x; a1 += w4[k].y*hv.y; a2 += w4[k].z*hv.z; a3 += w4[k].w*hv.w;
      }
      float pre = (a0+a1)+(a2+a3);
      gls[j] = (gt == 2) ? tanh_(pre) : sigf(pre);
      __syncthreads();                                   // bar1
      float ii = gls[d], ff = gls[128+d], gg = gls[256+d], oo = gls[384+d];
      float nc = ff*c + ii*gg;
      float nh = oo*tanh_(nc);
      bool ok = fabsf(nh-hp) <= EPS && fabsf(nc-c) <= EPS*fmaxf(1.f, fabsf(nc));
      c = nc; hp = nh;
      if (j < 128) {
        hls[j] = nh;
        unsigned long long bal = __ballot(ok);
        if ((j & 63) == 0) ip[j >> 6] = (bal == ~0ull) ? 1 : 0;
      }
      __syncthreads();                                   // bar2
      if (j < 128) hb[(t & R0M)*HDIM + j] = nh;          // ack absorbed by next bar1
      cnt = (ip[0] && ip[1]) ? cnt + 1 : 0;
      bool conv = (cnt >= WIN);
      bool ce = ((t & (CH-1)) == (CH-1));
      if (ce || conv) {
        __syncthreads();                                 // drain chunk's stores
        if (j == 0) {
          __threadfence();
          __hip_atomic_store(&prog0[b], t+1, __ATOMIC_RELEASE, __HIP_MEMORY_SCOPE_AGENT);
          if (!conv) {
            while ((t + 1 + CH) - __hip_atomic_load(&progP[b], __ATOMIC_ACQUIRE, __HIP_MEMORY_SCOPE_AGENT) > RING0)
              __builtin_amdgcn_s_sleep(2);
          }
        }
      }
      if (conv) { ++t; break; }
    }
    if (j == 0) {
      __threadfence();
      __hip_atomic_store(&prog0[b], t, __ATOMIC_RELEASE, __HIP_MEMORY_SCOPE_AGENT);
      __hip_atomic_store(&T0p1[b], t+1, __ATOMIC_RELEASE, __HIP_MEMORY_SCOPE_AGENT);
    }
  } else if (blk < 4) {
    // ===================== projector: xproj1 = w_ih1 . h0 + bias =====================
    const int b = blk & 1;
    float* s0ls = sm;
    const float bias = b_ih1[j] + b_hh1[j];
    const float* hb = hs0 + (size_t)b * RING0 * HDIM;
    float* xp1b = xproj1 + (size_t)b * RING1 * G4;
    int t = 0;
    for (;;) {
      if (j == 0) {
        int av, tv;
        for (;;) {
          av = __hip_atomic_load(&prog0[b], __ATOMIC_ACQUIRE, __HIP_MEMORY_SCOPE_AGENT);
          tv = __hip_atomic_load(&T0p1[b], __ATOMIC_ACQUIRE, __HIP_MEMORY_SCOPE_AGENT);
          int T0v = (tv == 0) ? SENT : tv - 1;
          if (T0v != SENT && t >= T0v) break;
          int need = t + CH; if (T0v != SENT && T0v < need) need = T0v;
          int cons = __hip_atomic_load(&progC[b], __ATOMIC_ACQUIRE, __HIP_MEMORY_SCOPE_AGENT);
          if (av >= need && need <= cons + RING1) break;
          __builtin_amdgcn_s_sleep(2);
        }
        ip2[0] = av; ip2[1] = tv;
      }
      __syncthreads();
      __threadfence();
      int av = ip2[0], tv = ip2[1];
      int T0v = (tv == 0) ? SENT : tv - 1;
      if (T0v != SENT && t >= T0v) break;
      int lim = (T0v != SENT && T0v < av) ? T0v : av;
      int C = min(CH, lim - t);
      for (int idx = j; idx < CH*HDIM; idx += 512) {
        int cc = idx >> 7, lane = idx & 127;
        float v = 0.f;
        if (cc < C) v = hb[((t + cc) & R0M)*HDIM + lane];
        s0ls[idx] = v;
      }
      __syncthreads();
      float xpa[CH];
      #pragma unroll
      for (int cc = 0; cc < CH; cc++) xpa[cc] = 0.f;
      const float4* s04 = (const float4*)s0ls;
      for (int k4 = 0; k4 < 32; k4++) {
        float wv0 = wih1T[(4*k4+0)*G4 + j];
        float wv1 = wih1T[(4*k4+1)*G4 + j];
        float wv2 = wih1T[(4*k4+2)*G4 + j];
        float wv3 = wih1T[(4*k4+3)*G4 + j];
        #pragma unroll
        for (int cc = 0; cc < CH; cc++) {
          float4 sv = s04[cc*32 + k4];
          xpa[cc] += wv0*sv.x + wv1*sv.y + wv2*sv.z + wv3*sv.w;
        }
      }
      for (int cc = 0; cc < C; cc++)
        xp1b[((t + cc) & R1M)*G4 + j] = xpa[cc] + bias;
      __syncthreads();
      if (j == 0) {
        __threadfence();
        __hip_atomic_store(&progP[b], t + C, __ATOMIC_RELEASE, __HIP_MEMORY_SCOPE_AGENT);
      }
      t += C;
    }
  } else {
    // ===================== layer-1 consumer + fused head =====================
    const int b = blk & 1;
    float* gls = sm; float* hls = sm + 512; float* s0b = sm + 640;
    float4 w4[32];
    const float4* wr = (const float4*)(w_hh1 + j*128);
    #pragma unroll
    for (int k = 0; k < 32; k++) w4[k] = wr[k];
    const float bias = b_ih1[j] + b_hh1[j];
    const int hn = j >> 5, hseg = j & 31;
    float4 wo = make_float4(0.f,0.f,0.f,0.f); float bo = 0.f;
    if (j < 320) { wo = ((const float4*)(w_out + hn*128))[hseg]; bo = b_out[hn]; }
    float* outb = out + (size_t)b * T_STEPS * NB;
    const float* hb = hs0 + (size_t)b * RING0 * HDIM;
    const float* xp1b = xproj1 + (size_t)b * RING1 * G4;
    if (j < HDIM) hls[j] = 0.f;
    const int d = j & 127;
    float c = 0.f, hp = 0.f;
    int cnt = 0;
    __syncthreads();
    int t = 0, T0fin = T_STEPS;

    // Phase A
    for (;;) {
      if (j == 0) {
        int pv, tv;
        for (;;) {
          pv = __hip_atomic_load(&progP[b], __ATOMIC_ACQUIRE, __HIP_MEMORY_SCOPE_AGENT);
          tv = __hip_atomic_load(&T0p1[b], __ATOMIC_ACQUIRE, __HIP_MEMORY_SCOPE_AGENT);
          int T0v = (tv == 0) ? SENT : tv - 1;
          if (T0v != SENT && t >= T0v) break;
          int need = t + CH; if (T0v != SENT && T0v < need) need = T0v;
          if (pv >= need) break;
          __builtin_amdgcn_s_sleep(2);
        }
        ip[2] = pv; ip[3] = tv;
      }
      __syncthreads();
      __threadfence();
      int pv = ip[2], tv = ip[3];
      int T0v = (tv == 0) ? SENT : tv - 1;
      if (T0v != SENT && t >= T0v) { T0fin = T0v; break; }
      int lim = (T0v != SENT && T0v < pv) ? T0v : pv;
      int C = min(CH, lim - t);
      float xpa[CH];
      #pragma unroll
      for (int cc = 0; cc < CH; cc++)
        xpa[cc] = xp1b[((t + cc) & R1M)*G4 + j];
      for (int cc = 0; cc < C; cc++) {
        float a0 = xpa[cc], a1 = 0.f, a2 = 0.f, a3 = 0.f;
        const float4* h4 = (const float4*)hls;
        #pragma unroll
        for (int k = 0; k < 32; k++) {
          float4 hv = h4[k];
          a0 += w4[k].x*hv.x; a1 += w4[k].y*hv.y; a2 += w4[k].z*hv.z; a3 += w4[k].w*hv.w;
        }
        float pre = (a0+a1)+(a2+a3);
        gls[j] = (gt == 2) ? tanh_(pre) : sigf(pre);
        __syncthreads();
        float ii = gls[d], ff = gls[128+d], gg = gls[256+d], oo = gls[384+d];
        float nc = ff*c + ii*gg;
        float nh = oo*tanh_(nc);
        c = nc; hp = nh;
        if (j < 128) hls[j] = nh;
        __syncthreads();
        if (j < 320) {
          float4 hv = ((const float4*)hls)[hseg];
          float acc = wo.x*hv.x + wo.y*hv.y + wo.z*hv.z + wo.w*hv.w;
          acc += __shfl_xor(acc, 1, 32);
          acc += __shfl_xor(acc, 2, 32);
          acc += __shfl_xor(acc, 4, 32);
          acc += __shfl_xor(acc, 8, 32);
          acc += __shfl_xor(acc, 16, 32);
          if (hseg == 0) outb[(t+cc)*NB + hn] = acc + bo;
        }
      }
      if (j == 0) __hip_atomic_store(&progC[b], t + C, __ATOMIC_RELEASE, __HIP_MEMORY_SCOPE_AGENT);
      t += C;
    }

    // Phase B
    if (T0fin < T_STEPS) {
      if (j < HDIM) s0b[j] = hb[((T0fin-1) & R0M)*HDIM + j];
      __syncthreads();
      float xps = bias;
      const float4* s04 = (const float4*)s0b;
      #pragma unroll
      for (int k4 = 0; k4 < 32; k4++) {
        float4 sv = s04[k4];
        xps += wih1T[(4*k4+0)*G4 + j]*sv.x + wih1T[(4*k4+1)*G4 + j]*sv.y
             + wih1T[(4*k4+2)*G4 + j]*sv.z + wih1T[(4*k4+3)*G4 + j]*sv.w;
      }
      for (; t < T_STEPS; ++t) {
        float a0 = xps, a1 = 0.f, a2 = 0.f, a3 = 0.f;
        const float4* h4 = (const float4*)hls;
        #pragma unroll
        for (int k = 0; k < 32; k++) {
          float4 hv = h4[k];
          a0 += w4[k].x*hv.x; a1 += w4[k].y*hv.y; a2 += w4[k].z*hv.z; a3 += w4[k].w*hv.w;
        }
        float pre = (a0+a1)+(a2+a3);
        gls[j] = (gt == 2) ? tanh_(pre) : sigf(pre);
        __syncthreads();
        float ii = gls[d], ff = gls[128+d], gg = gls[256+d], oo = gls[384+d];
        float nc = ff*c + ii*gg;
        float nh = oo*tanh_(nc);
        bool ok = fabsf(nh-hp) <= EPS && fabsf(nc-c) <= EPS*fmaxf(1.f, fabsf(nc));
        c = nc; hp = nh;
        if (j < 128) {
          hls[j] = nh;
          unsigned long long bal = __ballot(ok);
          if ((j & 63) == 0) ip[j >> 6] = (bal == ~0ull) ? 1 : 0;
        }
        __syncthreads();
        if (j < 320) {
          float4 hv = ((const float4*)hls)[hseg];
          float acc = wo.x*hv.x + wo.y*hv.y + wo.z*hv.z + wo.w*hv.w;
          acc += __shfl_xor(acc, 1, 32);
          acc += __shfl_xor(acc, 2, 32);
          acc += __shfl_xor(acc, 4, 32);
          acc += __shfl_xor(acc, 8, 32);
          acc += __shfl_xor(acc, 16, 32);
          if (hseg == 0) outb[t*NB + hn] = acc + bo;
        }
        cnt = (ip[0] && ip[1]) ? cnt + 1 : 0;
        if (cnt >= WIN) { ++t; break; }
      }
    }
    if (j < 320) {
      float4 hv = ((const float4*)hls)[hseg];
      float acc = wo.x*hv.x + wo.y*hv.y + wo.z*hv.z + wo.w*hv.w;
      acc += __shfl_xor(acc, 1, 32);
      acc += __shfl_xor(acc, 2, 32);
      acc += __shfl_xor(acc, 4, 32);
      acc += __shfl_xor(acc, 8, 32);
      acc += __shfl_xor(acc, 16, 32);
      if (hseg == 0) outst[b*NB + hn] = acc + bo;
    }
    __syncthreads();
    if (j == 0) {
      __threadfence();
      __hip_atomic_store(&T1p1[b], t + 1, __ATOMIC_RELEASE, __HIP_MEMORY_SCOPE_AGENT);
    }
  }
}

// ---------------- K4: fill t >= T1 with out* (stream-ordered after k23) ----------------
__global__ __launch_bounds__(256) void k4_fill(const int* __restrict__ T1p1,
                                               const float* __restrict__ outst,
                                               float* __restrict__ out)
{
  const int total = 2*T_STEPS*NB;
  const int T1a = T1p1[0] - 1, T1b = T1p1[1] - 1;
  for (int idx = blockIdx.x*256 + threadIdx.x; idx < total; idx += 4096*256) {
    int n = idx % NB;
    int bt = idx / NB;
    int t = bt % T_STEPS;
    int b = bt / T_STEPS;
    if (t >= (b ? T1b : T1a)) out[idx] = outst[b*NB + n];
  }
}

extern "C" void kernel_launch(void* const* d_in, const int* in_sizes, int n_in,
                              void* d_out, int out_size, void* d_ws, size_t ws_size,
                              hipStream_t stream) {
  const float* x     = (const float*)d_in[0];
  const float* w1    = (const float*)d_in[1];
  const float* b1    = (const float*)d_in[2];
  const float* w2    = (const float*)d_in[3];
  const float* b2    = (const float*)d_in[4];
  const float* w_ih0 = (const float*)d_in[5];
  const float* w_hh0 = (const float*)d_in[6];
  const float* b_ih0 = (const float*)d_in[7];
  const float* b_hh0 = (const float*)d_in[8];
  const float* w_ih1 = (const float*)d_in[9];
  const float* w_hh1 = (const float*)d_in[10];
  const float* b_ih1 = (const float*)d_in[11];
  const float* b_hh1 = (const float*)d_in[12];
  const float* w_out = (const float*)d_in[13];
  const float* b_out = (const float*)d_in[14];
  float* out = (float*)d_out;

  char* ws = (char*)d_ws;
  int*   flags   = (int*)  (ws + 0);                 // 64 B (memset)
  float* outst   = (float*)(ws + 64);                // 80 B
  float* wih1T   = (float*)(ws + 4096);              // 256 KB
  float* hs0     = (float*)(ws + 270336);            // 4 MB
  float* xproj1  = (float*)(ws + 270336 + 4194304);  // 4 MB

  hipMemsetAsync(flags, 0, 64, stream);
  k1_transpose<<<16, 256, 0, stream>>>(w_ih1, wih1T);
  k23_fused<<<6, 512, 0, stream>>>(x, w1, b1, w2, b2, w_ih0, b_ih0, b_hh0,
                                   w_hh0, w_hh1, b_ih1, b_hh1, w_out, b_out, wih1T,
                                   flags, outst, hs0, xproj1, out);
  k4_fill<<<4096, 256, 0, stream>>>(flags + 8, outst, out);
}

// Round 7
// 131.544 us; speedup vs baseline: 4.7460x; 1.0249x over previous
//
#include <hip/hip_runtime.h>

#define T_STEPS 144000
#define HDIM 128
#define G4 512
#define NB 10
#define CH 16
#define EPS 1e-4f
#define WIN 8
#define SENT 0x7fffffff
#define RING0 4096
#define R0M (RING0-1)
#define RING1 1024
#define R1M (RING1-1)

__device__ __forceinline__ float tanh_(float x){
  float e2 = __expf(-2.f*fabsf(x));
  float r = (1.f - e2)/(1.f + e2);
  return copysignf(r, x);
}

// ---------------- K1: blocks 0-15 transpose w_ih1; blocks 16-47 xproj0 ----------------
__global__ __launch_bounds__(256) void k1_prep(
    const float* __restrict__ x, const float* __restrict__ w1, const float* __restrict__ b1,
    const float* __restrict__ w2, const float* __restrict__ b2,
    const float* __restrict__ w_ih0, const float* __restrict__ b_ih0, const float* __restrict__ b_hh0,
    const float* __restrict__ w_ih1,
    float* __restrict__ wih1T, float* __restrict__ xproj0)
{
  const int blk = blockIdx.x, tid = threadIdx.x;
  if (blk < 16) {
    __shared__ float tile[32][33];
    const int ti = blk;
    const int tx = tid & 31, ty = tid >> 5;   // ty 0..7
    for (int tk = 0; tk < 4; tk++) {
      #pragma unroll
      for (int p = 0; p < 4; p++)
        tile[ty + 8*p][tx] = w_ih1[(ti*32 + ty + 8*p)*128 + tk*32 + tx];
      __syncthreads();
      #pragma unroll
      for (int p = 0; p < 4; p++)
        wih1T[(tk*32 + ty + 8*p)*G4 + ti*32 + tx] = tile[tx][ty + 8*p];
      __syncthreads();
    }
  } else {
    __shared__ float lat1[2][64];
    __shared__ __align__(16) float lat2[2][128];
    if (tid < 128) {
      int b = tid >> 6, jj = tid & 63;
      float a = b1[jj];
      #pragma unroll
      for (int k = 0; k < 16; k++) a += x[b*16+k] * w1[jj*16+k];
      lat1[b][jj] = fmaxf(a, 0.f);
    }
    __syncthreads();
    {
      int b = tid >> 7, jj = tid & 127;
      float a = b2[jj];
      #pragma unroll
      for (int k = 0; k < 64; k++) a += lat1[b][k] * w2[jj*64+k];
      lat2[b][jj] = fmaxf(a, 0.f);
    }
    __syncthreads();
    const int rid = (blk - 16)*32 + (tid >> 3);   // 0..1023
    const int b = rid >> 9, r = rid & 511, l8 = tid & 7;
    const float4* wv = (const float4*)(w_ih0 + r*128 + l8*16);
    const float4* lv = (const float4*)(&lat2[b][l8*16]);
    float a = 0.f;
    #pragma unroll
    for (int q = 0; q < 4; q++) {
      float4 w = wv[q], l = lv[q];
      a += w.x*l.x + w.y*l.y + w.z*l.z + w.w*l.w;
    }
    a += __shfl_xor(a, 1, 8);
    a += __shfl_xor(a, 2, 8);
    a += __shfl_xor(a, 4, 8);
    if (l8 == 0) xproj0[b*G4 + r] = a + b_ih0[r] + b_hh0[r];
  }
}

// flags: [0,1]=prog0  [2,3]=T0p1  [4,5]=progP  [6,7]=progC  [8,9]=T1p1
__global__ __launch_bounds__(512) void k23_fused(
    const float* __restrict__ xproj0,
    const float* __restrict__ w_hh0, const float* __restrict__ w_hh1,
    const float* __restrict__ b_ih1, const float* __restrict__ b_hh1,
    const float* __restrict__ w_out, const float* __restrict__ b_out,
    const float* __restrict__ wih1T,
    int* __restrict__ flags, float* __restrict__ outst,
    float* __restrict__ hs0, float* __restrict__ xproj1, float* __restrict__ out)
{
  __shared__ __align__(16) float hA[HDIM], hB[HDIM];
  __shared__ __align__(16) float s0ls[CH*HDIM];   // projector staging / consumer s0b
  __shared__ int okw[8];
  __shared__ int ipc[4];
  const int blk = blockIdx.x;
  const int j = threadIdx.x;
  const int d = j >> 2, g = j & 3;
  const int r = g*128 + d;                        // standard gate-row index
  int* prog0 = flags + 0; int* T0p1 = flags + 2; int* progP = flags + 4;
  int* progC = flags + 6; int* T1p1 = flags + 8;
  // branchless activation constants: act = as/(1+e^{-bs*pre}) + co
  const float as = (g == 2) ? 2.f : 1.f;
  const float bs = (g == 2) ? 2.f : 1.f;
  const float co = (g == 2) ? -1.f : 0.f;

  if (blk < 2) {
    // ===================== layer-0 producer =====================
    const int b = blk;
    const float xp = xproj0[b*G4 + r];
    float4 w4[32];
    const float4* wr = (const float4*)(w_hh0 + r*128);
    #pragma unroll
    for (int k = 0; k < 32; k++) w4[k] = wr[k];
    float* hb = hs0 + (size_t)b * RING0 * HDIM;
    if (g == 0) hA[d] = 0.f;
    float* hcur = hA; float* hnxt = hB;
    float c = 0.f, hp = 0.f;
    int cnt = 0;
    __syncthreads();
    int t = 0;
    for (; t < T_STEPS; ++t) {
      float a0 = xp, a1 = 0.f, a2 = 0.f, a3 = 0.f;
      const float4* h4 = (const float4*)hcur;
      #pragma unroll
      for (int k = 0; k < 32; k++) {
        float4 hv = h4[k];
        a0 += w4[k].x*hv.x; a1 += w4[k].y*hv.y; a2 += w4[k].z*hv.z; a3 += w4[k].w*hv.w;
      }
      float pre = ((a0+a1)+(a2+a3)) * bs;
      float act = as/(1.f + __expf(-pre)) + co;
      float ii = __shfl(act, 0, 4);
      float ff = __shfl(act, 1, 4);
      float gg = __shfl(act, 2, 4);
      float oo = __shfl(act, 3, 4);
      float nc = ff*c + ii*gg;
      float nh = oo*tanh_(nc);
      bool ok = fabsf(nh-hp) <= EPS && fabsf(nc-c) <= EPS*fmaxf(1.f, fabsf(nc));
      c = nc; hp = nh;
      if (g == 0) hnxt[d] = nh;
      unsigned long long bal = __ballot(ok);
      if ((j & 63) == 0) okw[j >> 6] = (bal == ~0ull) ? 1 : 0;
      __syncthreads();                                  // the ONE barrier
      if (g == 0) hb[(t & R0M)*HDIM + d] = nh;          // drains at chunk barrier
      { float* tmp = hcur; hcur = hnxt; hnxt = tmp; }
      int all8 = okw[0] & okw[1] & okw[2] & okw[3] & okw[4] & okw[5] & okw[6] & okw[7];
      cnt = all8 ? cnt + 1 : 0;
      bool conv = (cnt >= WIN);
      bool ce = ((t & (CH-1)) == (CH-1));
      if (ce || conv) {
        __syncthreads();                                // drain chunk's global stores
        if (j == 0) {
          __threadfence();
          __hip_atomic_store(&prog0[b], t+1, __ATOMIC_RELEASE, __HIP_MEMORY_SCOPE_AGENT);
          if (!conv) {
            while ((t + 1 + CH) - __hip_atomic_load(&progP[b], __ATOMIC_ACQUIRE, __HIP_MEMORY_SCOPE_AGENT) > RING0)
              __builtin_amdgcn_s_sleep(2);
          }
        }
      }
      if (conv) { ++t; break; }
    }
    if (j == 0) {
      __threadfence();
      __hip_atomic_store(&prog0[b], t, __ATOMIC_RELEASE, __HIP_MEMORY_SCOPE_AGENT);
      __hip_atomic_store(&T0p1[b], t+1, __ATOMIC_RELEASE, __HIP_MEMORY_SCOPE_AGENT);
    }
  } else if (blk < 4) {
    // ===================== projector: xproj1 = w_ih1 . h0 + bias =====================
    const int b = blk & 1;
    const float bias = b_ih1[j] + b_hh1[j];
    const float* hb = hs0 + (size_t)b * RING0 * HDIM;
    float* xp1b = xproj1 + (size_t)b * RING1 * G4;
    int t = 0;
    for (;;) {
      if (j == 0) {
        int av, tv;
        for (;;) {
          av = __hip_atomic_load(&prog0[b], __ATOMIC_ACQUIRE, __HIP_MEMORY_SCOPE_AGENT);
          tv = __hip_atomic_load(&T0p1[b], __ATOMIC_ACQUIRE, __HIP_MEMORY_SCOPE_AGENT);
          int T0v = (tv == 0) ? SENT : tv - 1;
          if (T0v != SENT && t >= T0v) break;
          int need = t + CH; if (T0v != SENT && T0v < need) need = T0v;
          int cons = __hip_atomic_load(&progC[b], __ATOMIC_ACQUIRE, __HIP_MEMORY_SCOPE_AGENT);
          if (av >= need && need <= cons + RING1) break;
          __builtin_amdgcn_s_sleep(2);
        }
        ipc[0] = av; ipc[1] = tv;
      }
      __syncthreads();
      __threadfence();
      int av = ipc[0], tv = ipc[1];
      int T0v = (tv == 0) ? SENT : tv - 1;
      if (T0v != SENT && t >= T0v) break;
      int lim = (T0v != SENT && T0v < av) ? T0v : av;
      int C = min(CH, lim - t);
      for (int idx = j; idx < CH*HDIM; idx += 512) {
        int cc = idx >> 7, lane = idx & 127;
        float v = 0.f;
        if (cc < C) v = hb[((t + cc) & R0M)*HDIM + lane];
        s0ls[idx] = v;
      }
      __syncthreads();
      float xpa[CH];
      #pragma unroll
      for (int cc = 0; cc < CH; cc++) xpa[cc] = 0.f;
      const float4* s04 = (const float4*)s0ls;
      for (int k4 = 0; k4 < 32; k4++) {
        float wv0 = wih1T[(4*k4+0)*G4 + j];
        float wv1 = wih1T[(4*k4+1)*G4 + j];
        float wv2 = wih1T[(4*k4+2)*G4 + j];
        float wv3 = wih1T[(4*k4+3)*G4 + j];
        #pragma unroll
        for (int cc = 0; cc < CH; cc++) {
          float4 sv = s04[cc*32 + k4];
          xpa[cc] += wv0*sv.x + wv1*sv.y + wv2*sv.z + wv3*sv.w;
        }
      }
      #pragma unroll
      for (int cc = 0; cc < CH; cc++) {
        if (cc >= C) break;
        xp1b[((t + cc) & R1M)*G4 + j] = xpa[cc] + bias;
      }
      __syncthreads();
      if (j == 0) {
        __threadfence();
        __hip_atomic_store(&progP[b], t + C, __ATOMIC_RELEASE, __HIP_MEMORY_SCOPE_AGENT);
      }
      t += C;
    }
  } else {
    // ===================== layer-1 consumer + fused head =====================
    const int b = blk & 1;
    float4 w4[32];
    const float4* wr = (const float4*)(w_hh1 + r*128);
    #pragma unroll
    for (int k = 0; k < 32; k++) w4[k] = wr[k];
    const float bias = b_ih1[r] + b_hh1[r];
    const int hn = j >> 5, hseg = j & 31;
    float4 wo = make_float4(0.f,0.f,0.f,0.f); float bo = 0.f;
    if (j < 320) { wo = ((const float4*)(w_out + hn*128))[hseg]; bo = b_out[hn]; }
    float* outb = out + (size_t)b * T_STEPS * NB;
    const float* hb = hs0 + (size_t)b * RING0 * HDIM;
    const float* xp1b = xproj1 + (size_t)b * RING1 * G4;
    if (g == 0) hA[d] = 0.f;
    float* hcur = hA; float* hnxt = hB;
    float c = 0.f, hp = 0.f;
    int cnt = 0;
    __syncthreads();
    int t = 0, T0fin = T_STEPS;

    // -------- Phase A: t < T0, input from xproj1 ring --------
    for (;;) {
      if (j == 0) {
        int pv, tv;
        for (;;) {
          pv = __hip_atomic_load(&progP[b], __ATOMIC_ACQUIRE, __HIP_MEMORY_SCOPE_AGENT);
          tv = __hip_atomic_load(&T0p1[b], __ATOMIC_ACQUIRE, __HIP_MEMORY_SCOPE_AGENT);
          int T0v = (tv == 0) ? SENT : tv - 1;
          if (T0v != SENT && t >= T0v) break;
          int need = t + CH; if (T0v != SENT && T0v < need) need = T0v;
          if (pv >= need) break;
          __builtin_amdgcn_s_sleep(2);
        }
        ipc[2] = pv; ipc[3] = tv;
      }
      __syncthreads();
      __threadfence();
      int pv = ipc[2], tv = ipc[3];
      int T0v = (tv == 0) ? SENT : tv - 1;
      if (T0v != SENT && t >= T0v) { T0fin = T0v; break; }
      int lim = (T0v != SENT && T0v < pv) ? T0v : pv;
      int C = min(CH, lim - t);
      float xpa[CH];
      #pragma unroll
      for (int cc = 0; cc < CH; cc++) {
        if (cc >= C) break;
        xpa[cc] = xp1b[((t + cc) & R1M)*G4 + r];
      }
      #pragma unroll
      for (int cc = 0; cc < CH; cc++) {
        if (cc >= C) break;
        float a0 = xpa[cc], a1 = 0.f, a2 = 0.f, a3 = 0.f;
        const float4* h4 = (const float4*)hcur;
        #pragma unroll
        for (int k = 0; k < 32; k++) {
          float4 hv = h4[k];
          a0 += w4[k].x*hv.x; a1 += w4[k].y*hv.y; a2 += w4[k].z*hv.z; a3 += w4[k].w*hv.w;
        }
        float pre = ((a0+a1)+(a2+a3)) * bs;
        float act = as/(1.f + __expf(-pre)) + co;
        float ii = __shfl(act, 0, 4);
        float ff = __shfl(act, 1, 4);
        float gg = __shfl(act, 2, 4);
        float oo = __shfl(act, 3, 4);
        float nc = ff*c + ii*gg;
        float nh = oo*tanh_(nc);
        c = nc; hp = nh;
        if (g == 0) hnxt[d] = nh;
        __syncthreads();                                // the ONE barrier
        if (j < 320) {
          float4 hv = ((const float4*)hnxt)[hseg];
          float acc = wo.x*hv.x + wo.y*hv.y + wo.z*hv.z + wo.w*hv.w;
          acc += __shfl_xor(acc, 1, 32);
          acc += __shfl_xor(acc, 2, 32);
          acc += __shfl_xor(acc, 4, 32);
          acc += __shfl_xor(acc, 8, 32);
          acc += __shfl_xor(acc, 16, 32);
          if (hseg == 0) outb[(t+cc)*NB + hn] = acc + bo;
        }
        { float* tmp = hcur; hcur = hnxt; hnxt = tmp; }
      }
      if (j == 0) __hip_atomic_store(&progC[b], t + C, __ATOMIC_RELEASE, __HIP_MEMORY_SCOPE_AGENT);
      t += C;
    }

    // -------- Phase B: constant input, convergence detect --------
    if (T0fin < T_STEPS) {
      if (j < HDIM) s0ls[j] = hb[((T0fin-1) & R0M)*HDIM + j];
      __syncthreads();
      float xps = bias;
      const float4* s04 = (const float4*)s0ls;
      #pragma unroll
      for (int k4 = 0; k4 < 32; k4++) {
        float4 sv = s04[k4];
        xps += wih1T[(4*k4+0)*G4 + r]*sv.x + wih1T[(4*k4+1)*G4 + r]*sv.y
             + wih1T[(4*k4+2)*G4 + r]*sv.z + wih1T[(4*k4+3)*G4 + r]*sv.w;
      }
      for (; t < T_STEPS; ++t) {
        float a0 = xps, a1 = 0.f, a2 = 0.f, a3 = 0.f;
        const float4* h4 = (const float4*)hcur;
        #pragma unroll
        for (int k = 0; k < 32; k++) {
          float4 hv = h4[k];
          a0 += w4[k].x*hv.x; a1 += w4[k].y*hv.y; a2 += w4[k].z*hv.z; a3 += w4[k].w*hv.w;
        }
        float pre = ((a0+a1)+(a2+a3)) * bs;
        float act = as/(1.f + __expf(-pre)) + co;
        float ii = __shfl(act, 0, 4);
        float ff = __shfl(act, 1, 4);
        float gg = __shfl(act, 2, 4);
        float oo = __shfl(act, 3, 4);
        float nc = ff*c + ii*gg;
        float nh = oo*tanh_(nc);
        bool ok = fabsf(nh-hp) <= EPS && fabsf(nc-c) <= EPS*fmaxf(1.f, fabsf(nc));
        c = nc; hp = nh;
        if (g == 0) hnxt[d] = nh;
        unsigned long long bal = __ballot(ok);
        if ((j & 63) == 0) okw[j >> 6] = (bal == ~0ull) ? 1 : 0;
        __syncthreads();                                // the ONE barrier
        if (j < 320) {
          float4 hv = ((const float4*)hnxt)[hseg];
          float acc = wo.x*hv.x + wo.y*hv.y + wo.z*hv.z + wo.w*hv.w;
          acc += __shfl_xor(acc, 1, 32);
          acc += __shfl_xor(acc, 2, 32);
          acc += __shfl_xor(acc, 4, 32);
          acc += __shfl_xor(acc, 8, 32);
          acc += __shfl_xor(acc, 16, 32);
          if (hseg == 0) outb[t*NB + hn] = acc + bo;
        }
        { float* tmp = hcur; hcur = hnxt; hnxt = tmp; }
        int all8 = okw[0] & okw[1] & okw[2] & okw[3] & okw[4] & okw[5] & okw[6] & okw[7];
        cnt = all8 ? cnt + 1 : 0;
        if (cnt >= WIN) { ++t; break; }
      }
    }
    // publish outstar + T1 (final h is in hcur after the last swap)
    if (j < 320) {
      float4 hv = ((const float4*)hcur)[hseg];
      float acc = wo.x*hv.x + wo.y*hv.y + wo.z*hv.z + wo.w*hv.w;
      acc += __shfl_xor(acc, 1, 32);
      acc += __shfl_xor(acc, 2, 32);
      acc += __shfl_xor(acc, 4, 32);
      acc += __shfl_xor(acc, 8, 32);
      acc += __shfl_xor(acc, 16, 32);
      if (hseg == 0) outst[b*NB + hn] = acc + bo;
    }
    __syncthreads();
    if (j == 0) {
      __threadfence();
      __hip_atomic_store(&T1p1[b], t + 1, __ATOMIC_RELEASE, __HIP_MEMORY_SCOPE_AGENT);
    }
  }
}

// ---------------- K4: fill t >= T1 with out* ----------------
__global__ __launch_bounds__(256) void k4_fill(const int* __restrict__ T1p1,
                                               const float* __restrict__ outst,
                                               float* __restrict__ out)
{
  const int total = 2*T_STEPS*NB;
  const int T1a = T1p1[0] - 1, T1b = T1p1[1] - 1;
  for (int idx = blockIdx.x*256 + threadIdx.x; idx < total; idx += 4096*256) {
    int n = idx % NB;
    int bt = idx / NB;
    int t = bt % T_STEPS;
    int b = bt / T_STEPS;
    if (t >= (b ? T1b : T1a)) out[idx] = outst[b*NB + n];
  }
}

extern "C" void kernel_launch(void* const* d_in, const int* in_sizes, int n_in,
                              void* d_out, int out_size, void* d_ws, size_t ws_size,
                              hipStream_t stream) {
  const float* x     = (const float*)d_in[0];
  const float* w1    = (const float*)d_in[1];
  const float* b1    = (const float*)d_in[2];
  const float* w2    = (const float*)d_in[3];
  const float* b2    = (const float*)d_in[4];
  const float* w_ih0 = (const float*)d_in[5];
  const float* w_hh0 = (const float*)d_in[6];
  const float* b_ih0 = (const float*)d_in[7];
  const float* b_hh0 = (const float*)d_in[8];
  const float* w_ih1 = (const float*)d_in[9];
  const float* w_hh1 = (const float*)d_in[10];
  const float* b_ih1 = (const float*)d_in[11];
  const float* b_hh1 = (const float*)d_in[12];
  const float* w_out = (const float*)d_in[13];
  const float* b_out = (const float*)d_in[14];
  float* out = (float*)d_out;

  char* ws = (char*)d_ws;
  int*   flags   = (int*)  (ws + 0);                 // 64 B (memset)
  float* outst   = (float*)(ws + 64);                // 80 B
  float* wih1T   = (float*)(ws + 4096);              // 256 KB
  float* xproj0  = (float*)(ws + 266240);            // 4 KB
  float* hs0     = (float*)(ws + 278528);            // 4 MB
  float* xproj1  = (float*)(ws + 278528 + 4194304);  // 4 MB

  hipMemsetAsync(flags, 0, 64, stream);
  k1_prep<<<48, 256, 0, stream>>>(x, w1, b1, w2, b2, w_ih0, b_ih0, b_hh0, w_ih1,
                                  wih1T, xproj0);
  k23_fused<<<6, 512, 0, stream>>>(xproj0, w_hh0, w_hh1, b_ih1, b_hh1,
                                   w_out, b_out, wih1T,
                                   flags, outst, hs0, xproj1, out);
  k4_fill<<<4096, 256, 0, stream>>>(flags + 8, outst, out);
}